// Round 11
// baseline (256.596 us; speedup 1.0000x reference)
//
#include <hip/hip_runtime.h>
#include <hip/hip_bf16.h>
#include <cstdint>
#include <cstddef>

// Problem constants
#define BB 4
#define SS 2048
#define DD 1024
#define HH 16
#define HDD 64

typedef __bf16 bf16_t;
typedef __bf16 bf16x8 __attribute__((ext_vector_type(8)));
typedef float f32x4 __attribute__((ext_vector_type(4)));
typedef unsigned u32x2 __attribute__((ext_vector_type(2)));

__device__ __forceinline__ unsigned short f2bf(float f) {
    unsigned u = __float_as_uint(f);
    unsigned r = (u + 0x7FFFu + ((u >> 16) & 1u)) >> 16;
    return (unsigned short)r;
}
__device__ __forceinline__ bf16_t f2bf16(float f) {
    return __builtin_bit_cast(bf16_t, f2bf(f));
}
__device__ __forceinline__ bf16x8 cvt8(float4 a, float4 b) {
    bf16x8 r;
    r[0] = f2bf16(a.x); r[1] = f2bf16(a.y);
    r[2] = f2bf16(a.z); r[3] = f2bf16(a.w);
    r[4] = f2bf16(b.x); r[5] = f2bf16(b.y);
    r[6] = f2bf16(b.z); r[7] = f2bf16(b.w);
    return r;
}
// packed f32x2 -> bf16x2 (RNE), lo16 = bf16(lo), hi16 = bf16(hi)
__device__ __forceinline__ unsigned cvtpk_bf16(float lo, float hi) {
    unsigned r;
    asm("v_cvt_pk_bf16_f32 %0, %1, %2" : "=v"(r) : "v"(lo), "v"(hi));
    return r;
}
// raw HW exp2: skips libm's denorm-guard sequence. 2^(-1e30) -> 0 in HW.
__device__ __forceinline__ float exp2_raw(float x) {
    float r;
    asm("v_exp_f32 %0, %1" : "=v"(r) : "v"(x));
    return r;
}

// async global->LDS, 16B per lane; LDS dest = wave-uniform base + lane*16
#define GLL16(gp, lp)                                                          \
    __builtin_amdgcn_global_load_lds(                                          \
        (const __attribute__((address_space(1))) void*)(gp),                   \
        (__attribute__((address_space(3))) void*)(lp), 16, 0, 0)

// ---------------------------------------------------------------------------
// fp32 -> bf16 converter, merged: blocks [0,4096) convert x (8M elems),
// blocks [4096,6144) convert the four 1M-elem weight matrices (512 each).
// ---------------------------------------------------------------------------
__global__ __launch_bounds__(256) void cvtall(
    const float* __restrict__ x,
    const float* __restrict__ w0, const float* __restrict__ w1,
    const float* __restrict__ w2, const float* __restrict__ w3,
    bf16_t* __restrict__ xb,
    bf16_t* __restrict__ o0, bf16_t* __restrict__ o1,
    bf16_t* __restrict__ o2, bf16_t* __restrict__ o3)
{
    const int bx = blockIdx.x;
    const float* in;
    bf16_t* out;
    size_t i;
    if (bx < 4096) {
        in = x; out = xb;
        i = (size_t)bx * 256 + threadIdx.x;
    } else {
        const int g = bx - 4096;
        const int s = g >> 9;          // 0..3
        in  = s == 0 ? w0 : s == 1 ? w1 : s == 2 ? w2 : w3;
        out = s == 0 ? o0 : s == 1 ? o1 : s == 2 ? o2 : o3;
        i = (size_t)(g & 511) * 256 + threadIdx.x;
    }
    const float4* p = (const float4*)in + i * 2;
    *(bf16x8*)(out + i * 8) = cvt8(p[0], p[1]);
}

// ---------------------------------------------------------------------------
// 256x128-tile GEMM, 512 threads = 8 waves (4m x 2n), 48KB LDS single-buf.
// R11 theory: both GEMMs were stuck at ~2.4 resident blocks/CU (Occupancy
// 29%, MfmaUtil 32%) -> latency/barrier stalls at low wave residency.
// BM=256/BN=128: (1) staging arithmetic intensity +33% (BM*BN/(BM+BN):
// 64->85 FLOP/B); (2) LDS-limited residency = 3 blocks x 8 waves =
// 6 waves/SIMD (vs 2.4); (3) zero-tail grids (qkv 768 = 3/CU, out 256 =
// 1/CU). Per-wave fragment work is byte-identical to the proven 128[2]
// kernel (64x64 output, same XOR-involution swizzle, same epilogues) —
// parameter change on the verified template, not a new sync structure.
// MODE 0: QKV epilogue (RoPE for Q/K, transposed write for V).
// MODE 1: fp32 row-major output (final projection).
// NT = N-tiles per m-row (24 for N=3072, 8 for N=1024).
// ---------------------------------------------------------------------------
template <int MODE, int NT>
__global__ __launch_bounds__(512, 2) void gemm256(
    const bf16_t* __restrict__ A, const bf16_t* __restrict__ W,
    bf16_t* __restrict__ Qb, bf16_t* __restrict__ Kb,
    bf16_t* __restrict__ Vt, float* __restrict__ Cf,
    const float* __restrict__ fcos, const float* __restrict__ fsin,
    float qscale)
{
    constexpr int K = 1024;
    __shared__ alignas(16) bf16_t lA[256 * 64];  // 32 KiB
    __shared__ alignas(16) bf16_t lB[128 * 64];  // 16 KiB

    const int tid  = threadIdx.x;
    const int w    = tid >> 6;          // 0..7
    const int lane = tid & 63;
    const int quad = lane >> 4;
    const int l16  = lane & 15;
    const int wm   = w >> 1;            // 0..3  (m sub-tile, 64 rows)
    const int wn   = w & 1;             // 0..1  (n sub-tile, 64 cols)

    // bijective XCD-chunked swizzle (grid % 8 == 0)
    const int lid     = blockIdx.y * NT + blockIdx.x;
    constexpr int CHK = (NT * 32) >> 3;          // logical tiles per XCD
    const int logical = (lid & 7) * CHK + (lid >> 3);
    const int m0      = (logical / NT) * 256;
    const int n0      = (logical % NT) * 128;

    f32x4 acc[4][4];
#pragma unroll
    for (int i = 0; i < 4; i++)
#pragma unroll
        for (int j = 0; j < 4; j++) acc[i][j] = (f32x4){0.f, 0.f, 0.f, 0.f};

    const int row8 = lane >> 3;   // row within an 8-row GLL group
    const int chk  = lane & 7;    // 16B chunk within the 128B row

    for (int k0 = 0; k0 < K; k0 += 64) {
        // A: 256 rows, wave stages rows [w*32, w*32+32) - 4 GLL16
#pragma unroll
        for (int i = 0; i < 4; ++i) {
            int rbase = w * 32 + i * 8;
            int row   = rbase + row8;
            GLL16(A + (size_t)(m0 + row) * K + k0 + ((chk ^ (row & 7)) * 8),
                  &lA[rbase * 64]);
        }
        // B: 128 rows, wave stages rows [w*16, w*16+16) - 2 GLL16
#pragma unroll
        for (int i = 0; i < 2; ++i) {
            int rbase = w * 16 + i * 8;
            int row   = rbase + row8;
            GLL16(W + (size_t)(n0 + row) * K + k0 + ((chk ^ (row & 7)) * 8),
                  &lB[rbase * 64]);
        }
        __syncthreads();
#pragma unroll
        for (int kk = 0; kk < 2; ++kk) {
            bf16x8 af[4], bfr[4];
#pragma unroll
            for (int mt = 0; mt < 4; ++mt) {
                const int row = wm * 64 + mt * 16 + l16;
                af[mt] = *(const bf16x8*)
                    &lA[row * 64 + (((kk * 4 + quad) ^ (row & 7)) * 8)];
            }
#pragma unroll
            for (int nt = 0; nt < 4; ++nt) {
                const int row = wn * 64 + nt * 16 + l16;
                bfr[nt] = *(const bf16x8*)
                    &lB[row * 64 + (((kk * 4 + quad) ^ (row & 7)) * 8)];
            }
#pragma unroll
            for (int mt = 0; mt < 4; ++mt)
#pragma unroll
                for (int nt = 0; nt < 4; ++nt)
                    acc[mt][nt] = __builtin_amdgcn_mfma_f32_16x16x32_bf16(
                        af[mt], bfr[nt], acc[mt][nt], 0, 0, 0);
        }
        __syncthreads();
    }

    if (MODE == 0) {
        const int sub = n0 >> 10;          // 0=Q, 1=K, 2=V (block-uniform)
        if (sub < 2) {
            // RoPE + scale, write bf16 (B,H,S,HD)
            unsigned short* Cu = (unsigned short*)(sub == 0 ? Qb : Kb);
            const float scale = sub == 0 ? qscale : 1.0f;
#pragma unroll
            for (int mt = 0; mt < 4; ++mt) {
#pragma unroll
                for (int nt = 0; nt < 4; ++nt) {
                    int col  = (n0 & 1023) + wn * 64 + nt * 16 + l16;
                    int h    = col >> 6;
                    int d    = col & 63;
                    int pidx = d >> 1;
                    bool even = (col & 1) == 0;
#pragma unroll
                    for (int r = 0; r < 4; ++r) {
                        int m = m0 + wm * 64 + mt * 16 + quad * 4 + r;
                        int b = m >> 11;   // / S
                        int s = m & 2047;  // % S
                        float v  = acc[mt][nt][r];
                        float p  = __shfl_xor(v, 1);
                        float c  = fcos[s * 32 + pidx];
                        float sn = fsin[s * 32 + pidx];
                        float o  = even ? (v * c - p * sn) : (p * sn + v * c);
                        Cu[(size_t)((b * HH + h) * SS + s) * HDD + d] =
                            f2bf(o * scale);
                    }
                }
            }
        } else {
            // V: write bf16 transposed (B,H,HD,S)
            unsigned short* Cu = (unsigned short*)Vt;
#pragma unroll
            for (int mt = 0; mt < 4; ++mt) {
#pragma unroll
                for (int nt = 0; nt < 4; ++nt) {
                    int col = (n0 & 1023) + wn * 64 + nt * 16 + l16;
                    int h = col >> 6, d = col & 63;
#pragma unroll
                    for (int r = 0; r < 4; ++r) {
                        int m = m0 + wm * 64 + mt * 16 + quad * 4 + r;
                        int b = m >> 11, s = m & 2047;
                        Cu[(size_t)((b * HH + h) * HDD + d) * SS + s] =
                            f2bf(acc[mt][nt][r]);
                    }
                }
            }
        }
    } else {
        // fp32 row-major output, N = 1024
#pragma unroll
        for (int mt = 0; mt < 4; ++mt) {
            int mrow = m0 + wm * 64 + mt * 16 + quad * 4;
#pragma unroll
            for (int nt = 0; nt < 4; ++nt) {
                int col = n0 + wn * 64 + nt * 16 + l16;
#pragma unroll
                for (int r = 0; r < 4; ++r)
                    Cf[(size_t)(mrow + r) * 1024 + col] = acc[mt][nt][r];
            }
        }
    }
}

// ---------------------------------------------------------------------------
// Flash attention v12 (UNCHANGED from R9 — current best: lean VALU body +
// stable 2 blocks/CU + zero-tail paired (T,15-T) 128-row tiles, 17 fat
// KVBLK=128 k-tiles per block, grid 512).
// ---------------------------------------------------------------------------
__global__ __launch_bounds__(256, 2) void attn(
    const bf16_t* __restrict__ Q, const bf16_t* __restrict__ Kt,
    const bf16_t* __restrict__ Vt, bf16_t* __restrict__ O)
{
    __shared__ alignas(16) bf16_t lK[128 * 64];    // 16 KiB, k-row x hd
    __shared__ alignas(16) bf16_t lV[2][64 * 64];  // 2 x 8 KiB, hd x k-col

    const int tid  = threadIdx.x;
    const int w    = tid >> 6;
    const int lane = tid & 63;
    const int quad = lane >> 4;
    const int l16  = lane & 15;

    // XCD-affinity decode: all 8 blocks of a given bh land on XCD bh&7.
    const int blk  = blockIdx.x;          // 0..511
    const int xcd  = blk & 7;
    const int rest = blk >> 3;            // 0..63
    const int g    = rest & 7;            // pair index 0..7
    const int bh   = ((rest >> 3) << 3) | xcd;

    const int b = bh >> 4, h = bh & 15;
    unsigned short* Ou = (unsigned short*)O;
    const bf16_t* Qb = Q  + (size_t)bh * SS * HDD;
    const bf16_t* Kb = Kt + (size_t)bh * SS * HDD;
    const bf16_t* Vb = Vt + (size_t)bh * HDD * SS;

    const int row8 = lane >> 3;            // 0..7 row within a group
    const int chk  = lane & 7;             // 16B chunk within a 128B row

    for (int phase = 0; phase < 2; ++phase) {
        const int Tp  = phase ? 15 - g : g;   // 128-row super-tile index
        const int q0  = Tp * 128 + w * 32;    // this wave's 32 q-rows
        const int nkb = Tp + 1;               // 128-wide k-tile count

        bf16x8 qf[2][2];
#pragma unroll
        for (int qs = 0; qs < 2; ++qs) {
            const bf16_t* qp =
                Qb + (size_t)(q0 + qs * 16 + l16) * HDD + quad * 8;
            qf[qs][0] = *(const bf16x8*)(qp);
            qf[qs][1] = *(const bf16x8*)(qp + 32);
        }

        f32x4 o[2][4];
        float ps[2];
#pragma unroll
        for (int qs = 0; qs < 2; ++qs) {
            ps[qs] = 0.f;
#pragma unroll
            for (int i = 0; i < 4; ++i) o[qs][i] = (f32x4){0.f, 0.f, 0.f, 0.f};
        }

        for (int t = 0; t < nkb; ++t) {
            const int kb2 = t * 128;

#pragma unroll
            for (int i = 0; i < 4; ++i) {
                int rbase = w * 32 + i * 8;
                int row   = rbase + row8;
                GLL16(Kb + (size_t)(kb2 + row) * HDD + ((chk ^ (row & 7)) * 8),
                      &lK[rbase * 64]);
            }
#pragma unroll
            for (int pp = 0; pp < 2; ++pp)
#pragma unroll
                for (int i = 0; i < 2; ++i) {
                    int rbase = w * 16 + i * 8;
                    int row   = rbase + row8;
                    GLL16(Vb + (size_t)row * SS + kb2 + pp * 64 +
                              ((chk ^ (row & 7)) * 8),
                          &lV[pp][rbase * 64]);
                }
            __syncthreads();

#pragma unroll
            for (int p = 0; p < 2; ++p) {
                const int kbp = kb2 + p * 64;
                if (kbp < q0 + 32) {       // wave-uniform: skip fully-masked
                    const bool diag = (kbp + 63 > q0);

                    bf16x8 kf[4][2];
#pragma unroll
                    for (int nt = 0; nt < 4; ++nt) {
                        const int row = p * 64 + nt * 16 + l16;
#pragma unroll
                        for (int hf = 0; hf < 2; ++hf)
                            kf[nt][hf] = *(const bf16x8*)
                                &lK[row * 64 +
                                    (((hf * 4 + quad) ^ (row & 7)) * 8)];
                    }

                    unsigned pk[4][2][2];
#pragma unroll
                    for (int nt = 0; nt < 4; ++nt) {
                        const int krow = kbp + nt * 16 + quad * 4;
#pragma unroll
                        for (int qs = 0; qs < 2; ++qs) {
                            f32x4 s = (f32x4){0.f, 0.f, 0.f, 0.f};
                            s = __builtin_amdgcn_mfma_f32_16x16x32_bf16(
                                kf[nt][0], qf[qs][0], s, 0, 0, 0);
                            s = __builtin_amdgcn_mfma_f32_16x16x32_bf16(
                                kf[nt][1], qf[qs][1], s, 0, 0, 0);
                            if (diag) {    // exec-skipped off the diagonal
                                const int qcol = q0 + qs * 16 + l16;
#pragma unroll
                                for (int r = 0; r < 4; ++r)
                                    if (krow + r > qcol) s[r] = -1e30f;
                            }
                            float ev[4];
#pragma unroll
                            for (int r = 0; r < 4; ++r) {
                                float e = exp2_raw(s[r]);  // scaled via Q-fold
                                ps[qs] += e;
                                ev[r] = e;
                            }
                            pk[nt][qs][0] = cvtpk_bf16(ev[0], ev[1]);
                            pk[nt][qs][1] = cvtpk_bf16(ev[2], ev[3]);
                        }
                    }

#pragma unroll
                    for (int kk = 0; kk < 2; ++kk) {
                        bf16x8 vfk[4];
#pragma unroll
                        for (int nt = 0; nt < 4; ++nt) {
                            const int row = nt * 16 + l16;
                            vfk[nt] = *(const bf16x8*)
                                &lV[p][row * 64 +
                                       (((kk * 4 + quad) ^ (row & 7)) * 8)];
                        }
#pragma unroll
                        for (int qs = 0; qs < 2; ++qs) {
                            u32x2 sA = __builtin_amdgcn_permlane32_swap(
                                pk[2 * kk][qs][0], pk[2 * kk + 1][qs][0],
                                false, false);
                            u32x2 sB = __builtin_amdgcn_permlane32_swap(
                                pk[2 * kk][qs][1], pk[2 * kk + 1][qs][1],
                                false, false);
                            u32x2 tA = __builtin_amdgcn_permlane16_swap(
                                sA.x, sA.y, false, false);
                            u32x2 tB = __builtin_amdgcn_permlane16_swap(
                                sB.x, sB.y, false, false);
                            union { unsigned d[4]; bf16x8 v; } pf;
                            pf.d[0] = tA.x;  // k-pair (0,1) of quad*8
                            pf.d[1] = tB.x;  // k-pair (2,3)
                            pf.d[2] = tA.y;  // k-pair (4,5)
                            pf.d[3] = tB.y;  // k-pair (6,7)
#pragma unroll
                            for (int nt = 0; nt < 4; ++nt)
                                o[qs][nt] =
                                    __builtin_amdgcn_mfma_f32_16x16x32_bf16(
                                        pf.v, vfk[nt], o[qs][nt], 0, 0, 0);
                        }
                    }
                }
            }
            __syncthreads();   // all reads done before next stage overwrites
        }

        // epilogue: quad-reduce row sums, redistribute, O/l, write bf16
#pragma unroll
        for (int qs = 0; qs < 2; ++qs) {
            float tsum = ps[qs];
            tsum += __shfl_xor(tsum, 16);
            tsum += __shfl_xor(tsum, 32);
            float inv[4];
#pragma unroll
            for (int r = 0; r < 4; ++r)
                inv[r] = 1.0f / __shfl(tsum, quad * 4 + r);
#pragma unroll
            for (int nt = 0; nt < 4; ++nt) {
                int d = nt * 16 + l16;
#pragma unroll
                for (int r = 0; r < 4; ++r) {
                    int s = q0 + qs * 16 + quad * 4 + r;
                    Ou[(size_t)(b * SS + s) * DD + h * HDD + d] =
                        f2bf(o[qs][nt][r] * inv[r]);
                }
            }
        }
    }
}

// ---------------------------------------------------------------------------
// Buffer plan.  TSZ = B*S*D bf16 = 16 MiB; WSZ = D*D bf16 = 2 MiB.
//   d_out (32 MiB fp32): [0,TSZ) = xb, [TSZ,2*TSZ) = Vt — both dead before
//     the final GEMM overwrites d_out (it reads only Ob, wb3).
//   ws: Qb | Kb | Ob | wb0..3 = 56 MiB.  wb0..wb2 contiguous = stacked QKV W.
// ---------------------------------------------------------------------------
extern "C" void kernel_launch(void* const* d_in, const int* in_sizes, int n_in,
                              void* d_out, int out_size, void* d_ws,
                              size_t ws_size, hipStream_t stream)
{
    const float* x    = (const float*)d_in[0];
    const float* fcos = (const float*)d_in[1];
    const float* fsin = (const float*)d_in[2];
    const float* wq   = (const float*)d_in[3];
    const float* wk   = (const float*)d_in[4];
    const float* wv   = (const float*)d_in[5];
    const float* wo   = (const float*)d_in[6];

    char* ws = (char*)d_ws;
    const size_t TSZ = (size_t)BB * SS * DD * sizeof(bf16_t);  // 16 MiB
    const size_t WSZ = (size_t)DD * DD * sizeof(bf16_t);       // 2 MiB
    bf16_t* Qb  = (bf16_t*)(ws);
    bf16_t* Kb  = (bf16_t*)(ws + TSZ);
    bf16_t* Ob  = (bf16_t*)(ws + 2 * TSZ);
    bf16_t* wb0 = (bf16_t*)(ws + 3 * TSZ);
    bf16_t* wb1 = (bf16_t*)(ws + 3 * TSZ + WSZ);
    bf16_t* wb2 = (bf16_t*)(ws + 3 * TSZ + 2 * WSZ);
    bf16_t* wb3 = (bf16_t*)(ws + 3 * TSZ + 3 * WSZ);
    bf16_t* xb  = (bf16_t*)d_out;
    bf16_t* Vt  = (bf16_t*)((char*)d_out + TSZ);

    cvtall<<<dim3(6144), dim3(256), 0, stream>>>(x, wq, wk, wv, wo,
                                                 xb, wb0, wb1, wb2, wb3);

    const float sscale = 0.125f * 1.44269504088896f;  // 1/sqrt(64)*log2(e)
    gemm256<0, 24><<<dim3(24, 32), dim3(512), 0, stream>>>(
        xb, wb0, Qb, Kb, Vt, nullptr, fcos, fsin, sscale);
    attn<<<dim3(512), dim3(256), 0, stream>>>(Qb, Kb, Vt, Ob);
    gemm256<1, 8><<<dim3(8, 32), dim3(512), 0, stream>>>(
        Ob, wb3, nullptr, nullptr, nullptr, (float*)d_out,
        fcos, fsin, 1.0f);
}

// Round 12
// 233.990 us; speedup vs baseline: 1.0966x; 1.0966x over previous
//
#include <hip/hip_runtime.h>
#include <hip/hip_bf16.h>
#include <cstdint>
#include <cstddef>

// Problem constants
#define BB 4
#define SS 2048
#define DD 1024
#define HH 16
#define HDD 64

typedef __bf16 bf16_t;
typedef __bf16 bf16x8 __attribute__((ext_vector_type(8)));
typedef float f32x4 __attribute__((ext_vector_type(4)));
typedef unsigned u32x2 __attribute__((ext_vector_type(2)));

__device__ __forceinline__ unsigned short f2bf(float f) {
    unsigned u = __float_as_uint(f);
    unsigned r = (u + 0x7FFFu + ((u >> 16) & 1u)) >> 16;
    return (unsigned short)r;
}
__device__ __forceinline__ bf16_t f2bf16(float f) {
    return __builtin_bit_cast(bf16_t, f2bf(f));
}
__device__ __forceinline__ bf16x8 cvt8(float4 a, float4 b) {
    bf16x8 r;
    r[0] = f2bf16(a.x); r[1] = f2bf16(a.y);
    r[2] = f2bf16(a.z); r[3] = f2bf16(a.w);
    r[4] = f2bf16(b.x); r[5] = f2bf16(b.y);
    r[6] = f2bf16(b.z); r[7] = f2bf16(b.w);
    return r;
}
// packed f32x2 -> bf16x2 (RNE), lo16 = bf16(lo), hi16 = bf16(hi)
__device__ __forceinline__ unsigned cvtpk_bf16(float lo, float hi) {
    unsigned r;
    asm("v_cvt_pk_bf16_f32 %0, %1, %2" : "=v"(r) : "v"(lo), "v"(hi));
    return r;
}
// raw HW exp2: skips libm's denorm-guard sequence. 2^(-1e30) -> 0 in HW.
__device__ __forceinline__ float exp2_raw(float x) {
    float r;
    asm("v_exp_f32 %0, %1" : "=v"(r) : "v"(x));
    return r;
}

// async global->LDS, 16B per lane; LDS dest = wave-uniform base + lane*16
#define GLL16(gp, lp)                                                          \
    __builtin_amdgcn_global_load_lds(                                          \
        (const __attribute__((address_space(1))) void*)(gp),                   \
        (__attribute__((address_space(3))) void*)(lp), 16, 0, 0)

// ---------------------------------------------------------------------------
// fp32 -> bf16 converter, merged: blocks [0,4096) convert x (8M elems),
// blocks [4096,6144) convert the four 1M-elem weight matrices (512 each).
// ---------------------------------------------------------------------------
__global__ __launch_bounds__(256) void cvtall(
    const float* __restrict__ x,
    const float* __restrict__ w0, const float* __restrict__ w1,
    const float* __restrict__ w2, const float* __restrict__ w3,
    bf16_t* __restrict__ xb,
    bf16_t* __restrict__ o0, bf16_t* __restrict__ o1,
    bf16_t* __restrict__ o2, bf16_t* __restrict__ o3)
{
    const int bx = blockIdx.x;
    const float* in;
    bf16_t* out;
    size_t i;
    if (bx < 4096) {
        in = x; out = xb;
        i = (size_t)bx * 256 + threadIdx.x;
    } else {
        const int g = bx - 4096;
        const int s = g >> 9;          // 0..3
        in  = s == 0 ? w0 : s == 1 ? w1 : s == 2 ? w2 : w3;
        out = s == 0 ? o0 : s == 1 ? o1 : s == 2 ? o2 : o3;
        i = (size_t)(g & 511) * 256 + threadIdx.x;
    }
    const float4* p = (const float4*)in + i * 2;
    *(bf16x8*)(out + i * 8) = cvt8(p[0], p[1]);
}

// ---------------------------------------------------------------------------
// Fused QKV projection: C(8192x3072) = xb(8192x1024) @ [wq;wk;wv]^T.
// R10 version EXACTLY (67us, 769 TF, 0 conflicts) — R11's 256-tile variant
// regressed per the guide's own tile-space data (128^2 best for 2-barrier
// loops); reverted.
// ---------------------------------------------------------------------------
__global__ __launch_bounds__(256, 2) void gemm_qkv(
    const bf16_t* __restrict__ A, const bf16_t* __restrict__ Wall,
    bf16_t* __restrict__ Qb, bf16_t* __restrict__ Kb,
    bf16_t* __restrict__ Vt,
    const float* __restrict__ fcos, const float* __restrict__ fsin,
    float qscale)
{
    constexpr int K = 1024;
    __shared__ alignas(16) bf16_t lA[128 * 64];
    __shared__ alignas(16) bf16_t lB[128 * 64];

    const int tid  = threadIdx.x;
    const int w    = tid >> 6;
    const int lane = tid & 63;
    const int quad = lane >> 4;
    const int l16  = lane & 15;
    const int wm   = w >> 1;
    const int wn   = w & 1;

    // XCD-chunked swizzle (1536 % 8 == 0 -> simple form is bijective)
    const int lid     = blockIdx.y * 24 + blockIdx.x;
    const int logical = (lid & 7) * 192 + (lid >> 3);
    const int m0      = (logical / 24) * 128;
    const int n0      = (logical % 24) * 128;
    const int sub     = n0 >> 10;        // 0=Q, 1=K, 2=V (block-uniform)

    f32x4 acc[4][4];
#pragma unroll
    for (int i = 0; i < 4; i++)
#pragma unroll
        for (int j = 0; j < 4; j++) acc[i][j] = (f32x4){0.f, 0.f, 0.f, 0.f};

    const int srow8 = lane >> 3;   // row within an 8-row GLL group
    const int slot  = lane & 7;    // 16B chunk within the 128B row

    for (int k0 = 0; k0 < K; k0 += 64) {
#pragma unroll
        for (int i = 0; i < 4; ++i) {
            int rbase = w * 32 + i * 8;
            int row   = rbase + srow8;
            int sc    = (slot ^ (row & 7)) * 8;   // swizzled source chunk
            GLL16(A + (size_t)(m0 + row) * K + k0 + sc, &lA[rbase * 64]);
            GLL16(Wall + (size_t)(n0 + row) * K + k0 + sc, &lB[rbase * 64]);
        }
        __syncthreads();
#pragma unroll
        for (int kk = 0; kk < 2; ++kk) {
            bf16x8 af[4], bfr[4];
#pragma unroll
            for (int mt = 0; mt < 4; ++mt) {
                const int row = wm * 64 + mt * 16 + l16;
                af[mt] = *(const bf16x8*)
                    &lA[row * 64 + (((kk * 4 + quad) ^ (row & 7)) * 8)];
            }
#pragma unroll
            for (int nt = 0; nt < 4; ++nt) {
                const int row = wn * 64 + nt * 16 + l16;
                bfr[nt] = *(const bf16x8*)
                    &lB[row * 64 + (((kk * 4 + quad) ^ (row & 7)) * 8)];
            }
#pragma unroll
            for (int mt = 0; mt < 4; ++mt)
#pragma unroll
                for (int nt = 0; nt < 4; ++nt)
                    acc[mt][nt] = __builtin_amdgcn_mfma_f32_16x16x32_bf16(
                        af[mt], bfr[nt], acc[mt][nt], 0, 0, 0);
        }
        __syncthreads();
    }

    if (sub < 2) {
        // RoPE + scale, write bf16 (B,H,S,HD)
        unsigned short* Cu = (unsigned short*)(sub == 0 ? Qb : Kb);
        const float scale = sub == 0 ? qscale : 1.0f;
#pragma unroll
        for (int mt = 0; mt < 4; ++mt) {
#pragma unroll
            for (int nt = 0; nt < 4; ++nt) {
                int col  = (n0 & 1023) + wn * 64 + nt * 16 + l16;
                int h    = col >> 6;
                int d    = col & 63;
                int pidx = d >> 1;
                bool even = (col & 1) == 0;
#pragma unroll
                for (int r = 0; r < 4; ++r) {
                    int m = m0 + wm * 64 + mt * 16 + quad * 4 + r;
                    int b = m >> 11;   // / S
                    int s = m & 2047;  // % S
                    float v  = acc[mt][nt][r];
                    float p  = __shfl_xor(v, 1);
                    float c  = fcos[s * 32 + pidx];
                    float sn = fsin[s * 32 + pidx];
                    float o  = even ? (v * c - p * sn) : (p * sn + v * c);
                    Cu[(size_t)((b * HH + h) * SS + s) * HDD + d] =
                        f2bf(o * scale);
                }
            }
        }
    } else {
        // V: write bf16 transposed (B,H,HD,S)
        unsigned short* Cu = (unsigned short*)Vt;
#pragma unroll
        for (int mt = 0; mt < 4; ++mt) {
#pragma unroll
            for (int nt = 0; nt < 4; ++nt) {
                int col = (n0 & 1023) + wn * 64 + nt * 16 + l16;
                int h = col >> 6, d = col & 63;
#pragma unroll
                for (int r = 0; r < 4; ++r) {
                    int m = m0 + wm * 64 + mt * 16 + quad * 4 + r;
                    int b = m >> 11, s = m & 2047;
                    Cu[(size_t)((b * HH + h) * HDD + d) * SS + s] =
                        f2bf(acc[mt][nt][r]);
                }
            }
        }
    }
}

// ---------------------------------------------------------------------------
// Final projection: C(8192x1024) = A @ W^T, fp32 row-major output.
// R12: BM x BN = 128 x 64 -> 1024 blocks = 4 blocks/CU (was 512 = 2/CU,
// grid-limited; ~265 TF, latency-exposed like pre-R9 attn). Per-wave output
// 32x64 (acc[2][4]); B staged with the attn V-pattern (2 GLL16/wave);
// LDS 24KB; same XOR-involution swizzle and 2-barrier template.
// ---------------------------------------------------------------------------
__global__ __launch_bounds__(256, 2) void gemm_out(
    const bf16_t* __restrict__ A, const bf16_t* __restrict__ W,
    float* __restrict__ Cf)
{
    constexpr int K = 1024, N = 1024;
    __shared__ alignas(16) bf16_t lA[128 * 64];  // 16 KiB
    __shared__ alignas(16) bf16_t lB[64 * 64];   //  8 KiB

    const int tid  = threadIdx.x;
    const int w    = tid >> 6;          // 0..3 = m sub-tile (32 rows)
    const int lane = tid & 63;
    const int quad = lane >> 4;
    const int l16  = lane & 15;

    // bijective XCD-chunked swizzle (1024 % 8 == 0); 16 n-tiles per m-row
    const int lid     = blockIdx.y * 16 + blockIdx.x;      // 0..1023
    const int logical = (lid & 7) * 128 + (lid >> 3);
    const int m0      = (logical >> 4) * 128;
    const int n0      = (logical & 15) * 64;

    f32x4 acc[2][4];
#pragma unroll
    for (int i = 0; i < 2; i++)
#pragma unroll
        for (int j = 0; j < 4; j++) acc[i][j] = (f32x4){0.f, 0.f, 0.f, 0.f};

    const int srow8 = lane >> 3;   // row within an 8-row GLL group
    const int slot  = lane & 7;    // 16B chunk within the 128B row

    for (int k0 = 0; k0 < K; k0 += 64) {
        // A: 128 rows, wave stages rows [w*32, w*32+32) - 4 GLL16
#pragma unroll
        for (int i = 0; i < 4; ++i) {
            int rbase = w * 32 + i * 8;
            int row   = rbase + srow8;
            GLL16(A + (size_t)(m0 + row) * K + k0 + ((slot ^ (row & 7)) * 8),
                  &lA[rbase * 64]);
        }
        // B: 64 rows, wave stages rows [w*16, w*16+16) - 2 GLL16
#pragma unroll
        for (int i = 0; i < 2; ++i) {
            int rbase = w * 16 + i * 8;
            int row   = rbase + srow8;
            GLL16(W + (size_t)(n0 + row) * K + k0 + ((slot ^ (row & 7)) * 8),
                  &lB[rbase * 64]);
        }
        __syncthreads();
#pragma unroll
        for (int kk = 0; kk < 2; ++kk) {
            bf16x8 af[2], bfr[4];
#pragma unroll
            for (int mt = 0; mt < 2; ++mt) {
                const int row = w * 32 + mt * 16 + l16;
                af[mt] = *(const bf16x8*)
                    &lA[row * 64 + (((kk * 4 + quad) ^ (row & 7)) * 8)];
            }
#pragma unroll
            for (int nt = 0; nt < 4; ++nt) {
                const int row = nt * 16 + l16;
                bfr[nt] = *(const bf16x8*)
                    &lB[row * 64 + (((kk * 4 + quad) ^ (row & 7)) * 8)];
            }
#pragma unroll
            for (int mt = 0; mt < 2; ++mt)
#pragma unroll
                for (int nt = 0; nt < 4; ++nt)
                    acc[mt][nt] = __builtin_amdgcn_mfma_f32_16x16x32_bf16(
                        af[mt], bfr[nt], acc[mt][nt], 0, 0, 0);
        }
        __syncthreads();
    }

#pragma unroll
    for (int mt = 0; mt < 2; ++mt) {
        int mrow = m0 + w * 32 + mt * 16 + quad * 4;
#pragma unroll
        for (int nt = 0; nt < 4; ++nt) {
            int col = n0 + nt * 16 + l16;
#pragma unroll
            for (int r = 0; r < 4; ++r)
                Cf[(size_t)(mrow + r) * N + col] = acc[mt][nt][r];
        }
    }
}

// ---------------------------------------------------------------------------
// Flash attention v12 (UNCHANGED from R9 — current best: lean VALU body +
// stable 2 blocks/CU + zero-tail paired (T,15-T) 128-row tiles, 17 fat
// KVBLK=128 k-tiles per block, grid 512).
// ---------------------------------------------------------------------------
__global__ __launch_bounds__(256, 2) void attn(
    const bf16_t* __restrict__ Q, const bf16_t* __restrict__ Kt,
    const bf16_t* __restrict__ Vt, bf16_t* __restrict__ O)
{
    __shared__ alignas(16) bf16_t lK[128 * 64];    // 16 KiB, k-row x hd
    __shared__ alignas(16) bf16_t lV[2][64 * 64];  // 2 x 8 KiB, hd x k-col

    const int tid  = threadIdx.x;
    const int w    = tid >> 6;
    const int lane = tid & 63;
    const int quad = lane >> 4;
    const int l16  = lane & 15;

    // XCD-affinity decode: all 8 blocks of a given bh land on XCD bh&7.
    const int blk  = blockIdx.x;          // 0..511
    const int xcd  = blk & 7;
    const int rest = blk >> 3;            // 0..63
    const int g    = rest & 7;            // pair index 0..7
    const int bh   = ((rest >> 3) << 3) | xcd;

    const int b = bh >> 4, h = bh & 15;
    unsigned short* Ou = (unsigned short*)O;
    const bf16_t* Qb = Q  + (size_t)bh * SS * HDD;
    const bf16_t* Kb = Kt + (size_t)bh * SS * HDD;
    const bf16_t* Vb = Vt + (size_t)bh * HDD * SS;

    const int row8 = lane >> 3;            // 0..7 row within a group
    const int chk  = lane & 7;             // 16B chunk within a 128B row

    for (int phase = 0; phase < 2; ++phase) {
        const int Tp  = phase ? 15 - g : g;   // 128-row super-tile index
        const int q0  = Tp * 128 + w * 32;    // this wave's 32 q-rows
        const int nkb = Tp + 1;               // 128-wide k-tile count

        bf16x8 qf[2][2];
#pragma unroll
        for (int qs = 0; qs < 2; ++qs) {
            const bf16_t* qp =
                Qb + (size_t)(q0 + qs * 16 + l16) * HDD + quad * 8;
            qf[qs][0] = *(const bf16x8*)(qp);
            qf[qs][1] = *(const bf16x8*)(qp + 32);
        }

        f32x4 o[2][4];
        float ps[2];
#pragma unroll
        for (int qs = 0; qs < 2; ++qs) {
            ps[qs] = 0.f;
#pragma unroll
            for (int i = 0; i < 4; ++i) o[qs][i] = (f32x4){0.f, 0.f, 0.f, 0.f};
        }

        for (int t = 0; t < nkb; ++t) {
            const int kb2 = t * 128;

#pragma unroll
            for (int i = 0; i < 4; ++i) {
                int rbase = w * 32 + i * 8;
                int row   = rbase + row8;
                GLL16(Kb + (size_t)(kb2 + row) * HDD + ((chk ^ (row & 7)) * 8),
                      &lK[rbase * 64]);
            }
#pragma unroll
            for (int pp = 0; pp < 2; ++pp)
#pragma unroll
                for (int i = 0; i < 2; ++i) {
                    int rbase = w * 16 + i * 8;
                    int row   = rbase + row8;
                    GLL16(Vb + (size_t)row * SS + kb2 + pp * 64 +
                              ((chk ^ (row & 7)) * 8),
                          &lV[pp][rbase * 64]);
                }
            __syncthreads();

#pragma unroll
            for (int p = 0; p < 2; ++p) {
                const int kbp = kb2 + p * 64;
                if (kbp < q0 + 32) {       // wave-uniform: skip fully-masked
                    const bool diag = (kbp + 63 > q0);

                    bf16x8 kf[4][2];
#pragma unroll
                    for (int nt = 0; nt < 4; ++nt) {
                        const int row = p * 64 + nt * 16 + l16;
#pragma unroll
                        for (int hf = 0; hf < 2; ++hf)
                            kf[nt][hf] = *(const bf16x8*)
                                &lK[row * 64 +
                                    (((hf * 4 + quad) ^ (row & 7)) * 8)];
                    }

                    unsigned pk[4][2][2];
#pragma unroll
                    for (int nt = 0; nt < 4; ++nt) {
                        const int krow = kbp + nt * 16 + quad * 4;
#pragma unroll
                        for (int qs = 0; qs < 2; ++qs) {
                            f32x4 s = (f32x4){0.f, 0.f, 0.f, 0.f};
                            s = __builtin_amdgcn_mfma_f32_16x16x32_bf16(
                                kf[nt][0], qf[qs][0], s, 0, 0, 0);
                            s = __builtin_amdgcn_mfma_f32_16x16x32_bf16(
                                kf[nt][1], qf[qs][1], s, 0, 0, 0);
                            if (diag) {    // exec-skipped off the diagonal
                                const int qcol = q0 + qs * 16 + l16;
#pragma unroll
                                for (int r = 0; r < 4; ++r)
                                    if (krow + r > qcol) s[r] = -1e30f;
                            }
                            float ev[4];
#pragma unroll
                            for (int r = 0; r < 4; ++r) {
                                float e = exp2_raw(s[r]);  // scaled via Q-fold
                                ps[qs] += e;
                                ev[r] = e;
                            }
                            pk[nt][qs][0] = cvtpk_bf16(ev[0], ev[1]);
                            pk[nt][qs][1] = cvtpk_bf16(ev[2], ev[3]);
                        }
                    }

#pragma unroll
                    for (int kk = 0; kk < 2; ++kk) {
                        bf16x8 vfk[4];
#pragma unroll
                        for (int nt = 0; nt < 4; ++nt) {
                            const int row = nt * 16 + l16;
                            vfk[nt] = *(const bf16x8*)
                                &lV[p][row * 64 +
                                       (((kk * 4 + quad) ^ (row & 7)) * 8)];
                        }
#pragma unroll
                        for (int qs = 0; qs < 2; ++qs) {
                            u32x2 sA = __builtin_amdgcn_permlane32_swap(
                                pk[2 * kk][qs][0], pk[2 * kk + 1][qs][0],
                                false, false);
                            u32x2 sB = __builtin_amdgcn_permlane32_swap(
                                pk[2 * kk][qs][1], pk[2 * kk + 1][qs][1],
                                false, false);
                            u32x2 tA = __builtin_amdgcn_permlane16_swap(
                                sA.x, sA.y, false, false);
                            u32x2 tB = __builtin_amdgcn_permlane16_swap(
                                sB.x, sB.y, false, false);
                            union { unsigned d[4]; bf16x8 v; } pf;
                            pf.d[0] = tA.x;  // k-pair (0,1) of quad*8
                            pf.d[1] = tB.x;  // k-pair (2,3)
                            pf.d[2] = tA.y;  // k-pair (4,5)
                            pf.d[3] = tB.y;  // k-pair (6,7)
#pragma unroll
                            for (int nt = 0; nt < 4; ++nt)
                                o[qs][nt] =
                                    __builtin_amdgcn_mfma_f32_16x16x32_bf16(
                                        pf.v, vfk[nt], o[qs][nt], 0, 0, 0);
                        }
                    }
                }
            }
            __syncthreads();   // all reads done before next stage overwrites
        }

        // epilogue: quad-reduce row sums, redistribute, O/l, write bf16
#pragma unroll
        for (int qs = 0; qs < 2; ++qs) {
            float tsum = ps[qs];
            tsum += __shfl_xor(tsum, 16);
            tsum += __shfl_xor(tsum, 32);
            float inv[4];
#pragma unroll
            for (int r = 0; r < 4; ++r)
                inv[r] = 1.0f / __shfl(tsum, quad * 4 + r);
#pragma unroll
            for (int nt = 0; nt < 4; ++nt) {
                int d = nt * 16 + l16;
#pragma unroll
                for (int r = 0; r < 4; ++r) {
                    int s = q0 + qs * 16 + quad * 4 + r;
                    Ou[(size_t)(b * SS + s) * DD + h * HDD + d] =
                        f2bf(o[qs][nt][r] * inv[r]);
                }
            }
        }
    }
}

// ---------------------------------------------------------------------------
// Buffer plan.  TSZ = B*S*D bf16 = 16 MiB; WSZ = D*D bf16 = 2 MiB.
//   d_out (32 MiB fp32): [0,TSZ) = xb, [TSZ,2*TSZ) = Vt — both dead before
//     the final GEMM overwrites d_out (it reads only Ob, wb3).
//   ws: Qb | Kb | Ob | wb0..3 = 56 MiB.  wb0..wb2 contiguous = stacked QKV W.
// ---------------------------------------------------------------------------
extern "C" void kernel_launch(void* const* d_in, const int* in_sizes, int n_in,
                              void* d_out, int out_size, void* d_ws,
                              size_t ws_size, hipStream_t stream)
{
    const float* x    = (const float*)d_in[0];
    const float* fcos = (const float*)d_in[1];
    const float* fsin = (const float*)d_in[2];
    const float* wq   = (const float*)d_in[3];
    const float* wk   = (const float*)d_in[4];
    const float* wv   = (const float*)d_in[5];
    const float* wo   = (const float*)d_in[6];

    char* ws = (char*)d_ws;
    const size_t TSZ = (size_t)BB * SS * DD * sizeof(bf16_t);  // 16 MiB
    const size_t WSZ = (size_t)DD * DD * sizeof(bf16_t);       // 2 MiB
    bf16_t* Qb  = (bf16_t*)(ws);
    bf16_t* Kb  = (bf16_t*)(ws + TSZ);
    bf16_t* Ob  = (bf16_t*)(ws + 2 * TSZ);
    bf16_t* wb0 = (bf16_t*)(ws + 3 * TSZ);
    bf16_t* wb1 = (bf16_t*)(ws + 3 * TSZ + WSZ);
    bf16_t* wb2 = (bf16_t*)(ws + 3 * TSZ + 2 * WSZ);
    bf16_t* wb3 = (bf16_t*)(ws + 3 * TSZ + 3 * WSZ);
    bf16_t* xb  = (bf16_t*)d_out;
    bf16_t* Vt  = (bf16_t*)((char*)d_out + TSZ);

    cvtall<<<dim3(6144), dim3(256), 0, stream>>>(x, wq, wk, wv, wo,
                                                 xb, wb0, wb1, wb2, wb3);

    const float sscale = 0.125f * 1.44269504088896f;  // 1/sqrt(64)*log2(e)
    gemm_qkv<<<dim3(24, 64), dim3(256), 0, stream>>>(xb, wb0, Qb, Kb, Vt,
                                                     fcos, fsin, sscale);
    attn<<<dim3(512), dim3(256), 0, stream>>>(Qb, Kb, Vt, Ob);
    gemm_out<<<dim3(16, 64), dim3(256), 0, stream>>>(Ob, wb3, (float*)d_out);
}